// Round 8
// baseline (812.133 us; speedup 1.0000x reference)
//
#include <hip/hip_runtime.h>
#include <hip/hip_cooperative_groups.h>
#include <math.h>

namespace cg = cooperative_groups;

#define D_MODEL 768
#define D_INNER 1536
#define D_STATE 16
#define D_CONV 4
#define DT_RANK 48
#define N_LAYER 3
#define BATCH 2
#define SEQLEN 1024
#define NROWS (BATCH * SEQLEN)   // 2048
#define XDBL_W (DT_RANK + 2 * D_STATE)  // 80
#define EPS 1e-5f

#define SDN 16                   // d-channels per scan block
#define NDG (D_INNER / SDN)      // 96
#define NSPLIT 4                 // sequence quarters
#define QSTEPS (SEQLEN / NSPLIT) // 256
#define SCLEN2 8                 // steps per chunk-thread (8 waves * 4 csub * 8 = 256)
#define KSPLIT_X 8               // x_proj split-K

typedef short bf16x8 __attribute__((ext_vector_type(8)));
typedef float f32x4 __attribute__((ext_vector_type(4)));

__device__ __forceinline__ ushort f2bf(float x) {
    union { float f; uint u; } v; v.f = x;
    uint r = v.u + 0x7fff + ((v.u >> 16) & 1);   // RNE
    return (ushort)(r >> 16);
}
__device__ __forceinline__ float bf2f(ushort x) {
    union { uint u; float f; } v; v.u = ((uint)x) << 16;
    return v.f;
}

__device__ __forceinline__ void gload_lds16(const void* g, void* l) {
    __builtin_amdgcn_global_load_lds(
        (const __attribute__((address_space(1))) unsigned int*)g,
        (__attribute__((address_space(3))) unsigned int*)l, 16, 0, 0);
}

// ---------------- f32 -> bf16 bulk convert ----------------
__global__ __launch_bounds__(256) void cvt_bf16_kernel(
    const float* __restrict__ s, ushort* __restrict__ d, int n4)
{
    int i = blockIdx.x * 256 + threadIdx.x;
    if (i >= n4) return;
    float4 v = ((const float4*)s)[i];
    ushort4 o;
    o.x = f2bf(v.x); o.y = f2bf(v.y); o.z = f2bf(v.z); o.w = f2bf(v.w);
    ((ushort4*)d)[i] = o;
}

// x_proj weights: [3][80][1536] f32 -> [3][128][1536] bf16 (rows >=80 zero)
__global__ __launch_bounds__(256) void cvt_xw_pad_kernel(
    const float* __restrict__ src, ushort* __restrict__ dst)
{
    const int per = 128 * 1536 / 4;
    int i = blockIdx.x * 256 + threadIdx.x;
    if (i >= 3 * per) return;
    int li = i / per, rem = i - li * per;
    int r = (rem * 4) / 1536, c = (rem * 4) % 1536;
    ushort4 o = make_ushort4(0, 0, 0, 0);
    if (r < XDBL_W) {
        const float* s = src + ((size_t)li * XDBL_W + r) * 1536 + c;
        o.x = f2bf(s[0]); o.y = f2bf(s[1]); o.z = f2bf(s[2]); o.w = f2bf(s[3]);
    }
    ((ushort4*)dst)[i] = o;
}

// dt_proj weights: [3][1536][48] f32 -> [3][1536][64] bf16 (cols >=48 zero)
__global__ __launch_bounds__(256) void cvt_dtw_pad_kernel(
    const float* __restrict__ src, ushort* __restrict__ dst)
{
    const int per = 1536 * 64 / 4;
    int i = blockIdx.x * 256 + threadIdx.x;
    if (i >= 3 * per) return;
    int li = i / per, rem = i - li * per;
    int r = (rem * 4) / 64, c = (rem * 4) % 64;
    ushort4 o = make_ushort4(0, 0, 0, 0);
    if (c < DT_RANK) {
        const float* s = src + ((size_t)li * 1536 + r) * DT_RANK + c;
        o.x = f2bf(s[0]); o.y = f2bf(s[1]); o.z = f2bf(s[2]); o.w = f2bf(s[3]);
    }
    ((ushort4*)dst)[i] = o;
}

// ---------------- add + rmsnorm ----------------
__global__ __launch_bounds__(256) void add_rmsnorm_kernel(
    const float* __restrict__ x, const float* __restrict__ res_in,
    const float* __restrict__ w, float* __restrict__ res_out,
    float* __restrict__ normed_f32, ushort* __restrict__ normed_bf)
{
    int row = blockIdx.x;
    int tid = threadIdx.x;
    const float* xr = x + row * D_MODEL;
    float v[3];
    float ss = 0.f;
#pragma unroll
    for (int i = 0; i < 3; i++) {
        int c = tid + i * 256;
        float t = xr[c];
        if (res_in) t += res_in[row * D_MODEL + c];
        v[i] = t;
        ss += t * t;
    }
    for (int off = 32; off; off >>= 1) ss += __shfl_xor(ss, off, 64);
    __shared__ float red[4];
    if ((tid & 63) == 0) red[tid >> 6] = ss;
    __syncthreads();
    float tot = red[0] + red[1] + red[2] + red[3];
    float scale = rsqrtf(tot * (1.f / D_MODEL) + EPS);
#pragma unroll
    for (int i = 0; i < 3; i++) {
        int c = tid + i * 256;
        if (res_out) res_out[row * D_MODEL + c] = v[i];
        float o = v[i] * scale * w[c];
        if (normed_f32) normed_f32[row * D_MODEL + c] = o;
        if (normed_bf)  normed_bf[row * D_MODEL + c] = f2bf(o);
    }
}

// ---------------- bf16 MFMA GEMM: C[M,N] = A[M,K] @ W[N,K]^T ----------------
// EPI: 0 none, 1 softplus(acc+bias[n]). SPLITK>1: blockIdx.z slices K, partial
// C at z*M*ldc. OUTBF: 1 -> bf16 output.
template <int BM, int BN, int EPI, int SPLITK, int OUTBF>
__global__ __launch_bounds__(256) void gemm_mfma_kernel(
    const ushort* __restrict__ A, const ushort* __restrict__ W,
    const float* __restrict__ bias, void* __restrict__ Cv,
    int ldc, int Nout, int M, int K)
{
    constexpr int TM = BM / 32;
    constexpr int TN = BN / 32;
    __shared__ __attribute__((aligned(16))) ushort As[BM * 64];
    __shared__ __attribute__((aligned(16))) ushort Ws[BN * 64];
    const int t = threadIdx.x;
    const int lane = t & 63, w = t >> 6;
    const int ln15 = lane & 15, q = lane >> 4;
    const int row0 = blockIdx.y * BM, col0 = blockIdx.x * BN;
    const int wm0 = (w & 1) * (BM / 2), wn0 = (w >> 1) * (BN / 2);

    int kper = K / SPLITK;
    int kz = (SPLITK > 1) ? blockIdx.z * kper : 0;
    float* Cf = (float*)Cv;
    ushort* Cb = (ushort*)Cv;
    if (SPLITK > 1) {
        Cf += (size_t)blockIdx.z * M * ldc;
        Cb += (size_t)blockIdx.z * M * ldc;
    }

    f32x4 acc[TM][TN];
#pragma unroll
    for (int i = 0; i < TM; i++)
#pragma unroll
        for (int j = 0; j < TN; j++) acc[i][j] = (f32x4){0.f, 0.f, 0.f, 0.f};

    for (int k0 = kz; k0 < kz + kper; k0 += 64) {
        __syncthreads();
#pragma unroll
        for (int i = 0; i < BM / 32; i++) {
            int p = (i * 4 + w) * 64 + lane;
            int r = p >> 3, s = p & 7;
            int g = s ^ (r & 7);
            gload_lds16(A + (size_t)(row0 + r) * K + k0 + g * 8, &As[p * 8]);
        }
#pragma unroll
        for (int i = 0; i < BN / 32; i++) {
            int p = (i * 4 + w) * 64 + lane;
            int r = p >> 3, s = p & 7;
            int g = s ^ (r & 7);
            gload_lds16(W + (size_t)(col0 + r) * K + k0 + g * 8, &Ws[p * 8]);
        }
        __syncthreads();
#pragma unroll
        for (int ks = 0; ks < 2; ks++) {
            bf16x8 af[TM], wf[TN];
#pragma unroll
            for (int im = 0; im < TM; im++) {
                int m = wm0 + im * 16 + ln15;
                int slot = (ks * 4 + q) ^ (m & 7);
                af[im] = *(const bf16x8*)&As[m * 64 + slot * 8];
            }
#pragma unroll
            for (int jn = 0; jn < TN; jn++) {
                int n = wn0 + jn * 16 + ln15;
                int slot = (ks * 4 + q) ^ (n & 7);
                wf[jn] = *(const bf16x8*)&Ws[n * 64 + slot * 8];
            }
#pragma unroll
            for (int im = 0; im < TM; im++)
#pragma unroll
                for (int jn = 0; jn < TN; jn++)
                    acc[im][jn] = __builtin_amdgcn_mfma_f32_16x16x32_bf16(
                        af[im], wf[jn], acc[im][jn], 0, 0, 0);
        }
    }
#pragma unroll
    for (int im = 0; im < TM; im++) {
#pragma unroll
        for (int jn = 0; jn < TN; jn++) {
            int rr = row0 + wm0 + im * 16 + q * 4;
            int cc = col0 + wn0 + jn * 16 + ln15;
            if (cc < Nout) {
#pragma unroll
                for (int r = 0; r < 4; r++) {
                    float v = acc[im][jn][r];
                    if (EPI == 1) {
                        v += bias[cc];
                        v = (v > 20.f) ? v : log1pf(__expf(v));
                    }
                    if (OUTBF) Cb[(size_t)(rr + r) * ldc + cc] = f2bf(v);
                    else       Cf[(size_t)(rr + r) * ldc + cc] = v;
                }
            }
        }
    }
}

// ---------------- x_proj split-K reduce: xdbl f32 + padded bf16 dt-part ----
__global__ __launch_bounds__(256) void xreduce_kernel(
    const float* __restrict__ Cp, float* __restrict__ xdbl,
    ushort* __restrict__ xdt)
{
    const int S4 = NROWS * XDBL_W / 4;
    int i = blockIdx.x * 256 + threadIdx.x;
    if (i >= S4) return;
    const float4* p = (const float4*)Cp;
    float4 o = p[i];
#pragma unroll
    for (int z = 1; z < KSPLIT_X; z++) {
        float4 a = p[i + (size_t)z * S4];
        o.x += a.x; o.y += a.y; o.z += a.z; o.w += a.w;
    }
    ((float4*)xdbl)[i] = o;
    int row = (i * 4) / XDBL_W, c0 = (i * 4) % XDBL_W;
    if (c0 < DT_RANK) {
        ushort4 b;
        b.x = f2bf(o.x); b.y = f2bf(o.y); b.z = f2bf(o.z); b.w = f2bf(o.w);
        *(ushort4*)&xdt[(size_t)row * 64 + c0] = b;
    } else if (c0 < 64) {
        *(ushort4*)&xdt[(size_t)row * 64 + c0] = make_ushort4(0, 0, 0, 0);
    }
}

// ---------------- depthwise causal conv1d (k=4) + SiLU (bf16 in/out) -------
__global__ __launch_bounds__(256) void conv_silu_kernel(
    const ushort* __restrict__ xzbf, const float* __restrict__ cw,
    const float* __restrict__ cb, ushort* __restrict__ out_bf)
{
    int idx = blockIdx.x * 256 + threadIdx.x;
    int d = idx % D_INNER;
    int bl = idx / D_INNER;
    int l = bl % SEQLEN;
    float s = cb[d];
    const ushort* xp = xzbf + (size_t)bl * (2 * D_INNER) + d;
#pragma unroll
    for (int k = 0; k < D_CONV; k++) {
        int ls = l - (D_CONV - 1) + k;
        if (ls >= 0) s += cw[d * D_CONV + k] * bf2f(xp[(k - (D_CONV - 1)) * (2 * D_INNER)]);
    }
    float sil = s / (1.f + __expf(-s));
    out_bf[(size_t)bl * D_INNER + d] = f2bf(sil);
}

// ---------------- cooperative chunked selective scan, 4-way seq split -------
// 768 blocks x 512 thr, one dispatch. Block = (b, dg, quarter): dsub=lane&15,
// csub=lane>>4, 8 waves -> 32 chunks x 8 steps = 256 steps. Phase 1 reads
// inputs once, publishes per-quarter (P,H) totals; grid.sync(); lookback
// compose (<=3 L2 summary reads); phase 2 rescans with true h0 and emits y.
// Residency: __launch_bounds__(512,6) caps VGPR at 85 -> worst case 3
// blocks/CU x 256 = 768 = grid (coop launch validates this); LDS 17.4 KB.
__global__ __launch_bounds__(512, 6) void scan_coop_kernel(
    const ushort* __restrict__ ubf, const float* __restrict__ delta,
    const float* __restrict__ A_log, const float* __restrict__ xdbl,
    const float* __restrict__ Dskip, const ushort* __restrict__ xzbf,
    float* __restrict__ summ, ushort* __restrict__ ybf)
{
    __shared__ float PL[8][SDN * 17];
    __shared__ float HL[8][SDN * 17];
    const int t = threadIdx.x;
    const int lane = t & 63;
    const int w = t >> 6;
    const int dsub = lane & 15;
    const int csub = lane >> 4;
    const int bid = blockIdx.x;
    const int qq = bid & 3;
    const int rest = bid >> 2;        // b*NDG + dg
    const int b = rest / NDG;
    const int dg = rest % NDG;
    const int d = dg * SDN + dsub;
    const int c = w * 4 + csub;
    const int l0 = qq * QSTEPS + c * SCLEN2;

    float a2[D_STATE];
#pragma unroll
    for (int n = 0; n < D_STATE; n++)
        a2[n] = -__expf(A_log[d * D_STATE + n]) * 1.44269504f;

    const size_t base = (size_t)b * SEQLEN * D_INNER + d;
    const float* dtp = delta + base;
    const ushort* up = ubf + base;
    const float* xrow = xdbl + (size_t)b * SEQLEN * XDBL_W;

    float h[D_STATE], P[D_STATE];
#pragma unroll
    for (int n = 0; n < D_STATE; n++) { h[n] = 0.f; P[n] = 1.f; }

    // ---- phase 1: chunk transfer (read #1) ----
    for (int i = 0; i < SCLEN2; i++) {
        const int l = l0 + i;
        float dt = dtp[(size_t)l * D_INNER];
        float uu = bf2f(up[(size_t)l * D_INNER]);
        const float4* Bv = (const float4*)(xrow + (size_t)l * XDBL_W + DT_RANK);
        float4 q0 = Bv[0], q1 = Bv[1], q2 = Bv[2], q3 = Bv[3];
        float Bf[D_STATE] = {q0.x,q0.y,q0.z,q0.w, q1.x,q1.y,q1.z,q1.w,
                             q2.x,q2.y,q2.z,q2.w, q3.x,q3.y,q3.z,q3.w};
        float dtu = dt * uu;
#pragma unroll
        for (int n = 0; n < D_STATE; n++) {
            float e = __builtin_amdgcn_exp2f(dt * a2[n]);
            P[n] *= e;
            h[n] = e * h[n] + dtu * Bf[n];
        }
    }
    // intra-wave inclusive scan over csub
#pragma unroll
    for (int n = 0; n < D_STATE; n++) {
        float Pp = __shfl(P[n], lane - 16, 64);
        float Hp = __shfl(h[n], lane - 16, 64);
        bool act = csub >= 1;
        h[n] = act ? P[n] * Hp + h[n] : h[n];
        P[n] = act ? P[n] * Pp : P[n];
    }
#pragma unroll
    for (int n = 0; n < D_STATE; n++) {
        float Pp = __shfl(P[n], lane - 32, 64);
        float Hp = __shfl(h[n], lane - 32, 64);
        bool act = csub >= 2;
        h[n] = act ? P[n] * Hp + h[n] : h[n];
        P[n] = act ? P[n] * Pp : P[n];
    }
    if (csub == 3) {
#pragma unroll
        for (int n = 0; n < D_STATE; n++) {
            PL[w][dsub * 17 + n] = P[n];
            HL[w][dsub * 17 + n] = h[n];
        }
    }
    __syncthreads();

    // ---- publish this quarter's (P,H) totals ----
    if (t < SDN * D_STATE) {
        const int d2 = t >> 4, n2 = t & 15;
        float hin = 0.f, pin = 1.f;
        for (int ww = 0; ww < 8; ww++) {
            float Pw = PL[ww][d2 * 17 + n2];
            float Hw = HL[ww][d2 * 17 + n2];
            hin = Pw * hin + Hw;
            pin *= Pw;
        }
        float* so = summ + ((size_t)rest * NSPLIT + qq) * 512;
        so[t] = pin;
        so[256 + t] = hin;
    }

    cg::this_grid().sync();

    // ---- lookback compose: seed with quarters 0..qq-1, distribute to waves --
    if (t < SDN * D_STATE) {
        const int d2 = t >> 4, n2 = t & 15;
        float hin = 0.f;
        for (int z = 0; z < qq; z++) {
            const float* so = summ + ((size_t)rest * NSPLIT + z) * 512;
            hin = so[t] * hin + so[256 + t];
        }
        for (int ww = 0; ww < 8; ww++) {
            float Pw = PL[ww][d2 * 17 + n2];
            float Hw = HL[ww][d2 * 17 + n2];
            HL[ww][d2 * 17 + n2] = hin;
            hin = Pw * hin + Hw;
        }
    }
    __syncthreads();

    // ---- per-thread chunk-incoming state ----
#pragma unroll
    for (int n = 0; n < D_STATE; n++) {
        float Win = HL[w][dsub * 17 + n];
        float Pe = __shfl(P[n], lane - 16, 64);
        float He = __shfl(h[n], lane - 16, 64);
        h[n] = (csub == 0) ? Win : Pe * Win + He;
    }

    // ---- phase 2: rescan (read #2) + gate + emit y ----
    const float Dsk = Dskip[d];
    const ushort* zp = xzbf + (size_t)b * SEQLEN * (2 * D_INNER) + D_INNER + d;
    ushort* yp = ybf + base;
    for (int i = 0; i < SCLEN2; i++) {
        const int l = l0 + i;
        float dt = dtp[(size_t)l * D_INNER];
        float uu = bf2f(up[(size_t)l * D_INNER]);
        float zz = bf2f(zp[(size_t)l * (2 * D_INNER)]);
        const float4* Bv = (const float4*)(xrow + (size_t)l * XDBL_W + DT_RANK);
        float4 q0 = Bv[0], q1 = Bv[1], q2 = Bv[2], q3 = Bv[3];
        float4 r0 = Bv[4], r1 = Bv[5], r2 = Bv[6], r3 = Bv[7];
        float Bf[D_STATE] = {q0.x,q0.y,q0.z,q0.w, q1.x,q1.y,q1.z,q1.w,
                             q2.x,q2.y,q2.z,q2.w, q3.x,q3.y,q3.z,q3.w};
        float Cf[D_STATE] = {r0.x,r0.y,r0.z,r0.w, r1.x,r1.y,r1.z,r1.w,
                             r2.x,r2.y,r2.z,r2.w, r3.x,r3.y,r3.z,r3.w};
        float dtu = dt * uu;
        float acc = 0.f;
#pragma unroll
        for (int n = 0; n < D_STATE; n++) {
            float e = __builtin_amdgcn_exp2f(dt * a2[n]);
            h[n] = e * h[n] + dtu * Bf[n];
            acc += h[n] * Cf[n];
        }
        float yy = acc + uu * Dsk;
        float ee = __builtin_amdgcn_exp2f(-zz * 1.44269504f);
        float sil = zz * __builtin_amdgcn_rcpf(1.f + ee);
        yp[(size_t)l * D_INNER] = f2bf(yy * sil);
    }
}

extern "C" void kernel_launch(void* const* d_in, const int* in_sizes, int n_in,
                              void* d_out, int out_size, void* d_ws, size_t ws_size,
                              hipStream_t stream)
{
    const float* hs        = (const float*)d_in[0];
    const float* norm_w    = (const float*)d_in[1];
    const float* in_proj_w = (const float*)d_in[2];
    const float* conv_w    = (const float*)d_in[3];
    const float* conv_b    = (const float*)d_in[4];
    const float* x_proj_w  = (const float*)d_in[5];
    const float* dt_proj_w = (const float*)d_in[6];
    const float* dt_proj_b = (const float*)d_in[7];
    const float* A_log     = (const float*)d_in[8];
    const float* D_skip    = (const float*)d_in[9];
    const float* out_proj_w= (const float*)d_in[10];
    const float* norm_f_w  = (const float*)d_in[11];

    float* ws = (float*)d_ws;
    float* residual = ws;                                   // 2048*768
    float* hidden   = residual + NROWS * D_MODEL;           // 2048*768
    float* xdbl     = hidden + NROWS * D_MODEL;             // 2048*80
    float* delta    = xdbl + NROWS * XDBL_W;                // 2048*1536
    float* xpart    = delta + NROWS * D_INNER;              // 8*2048*80
    float* summ     = xpart + (size_t)KSPLIT_X * NROWS * XDBL_W; // 192*4*512
    ushort* xzbf    = (ushort*)(summ + (size_t)BATCH * NDG * NSPLIT * 512);
    ushort* normbf  = xzbf + (size_t)NROWS * 2 * D_INNER;   // 2048*768
    ushort* ybf     = normbf + NROWS * D_MODEL;             // 2048*1536
    ushort* xconvbf = ybf + NROWS * D_INNER;                // 2048*1536
    ushort* xdtbf   = xconvbf + NROWS * D_INNER;            // 2048*64
    ushort* win_bf  = xdtbf + NROWS * 64;                   // 3*3072*768
    ushort* wout_bf = win_bf + (size_t)N_LAYER * 2 * D_INNER * D_MODEL;
    ushort* xw_pad  = wout_bf + (size_t)N_LAYER * D_MODEL * D_INNER; // 3*128*1536
    ushort* dtw_pad = xw_pad + (size_t)N_LAYER * 128 * 1536;          // 3*1536*64

    {
        int n_in4  = N_LAYER * 2 * D_INNER * D_MODEL / 4;
        int n_out4 = N_LAYER * D_MODEL * D_INNER / 4;
        cvt_bf16_kernel<<<(n_in4 + 255) / 256, 256, 0, stream>>>(in_proj_w, win_bf, n_in4);
        cvt_bf16_kernel<<<(n_out4 + 255) / 256, 256, 0, stream>>>(out_proj_w, wout_bf, n_out4);
        cvt_xw_pad_kernel<<<(3 * 128 * 1536 / 4 + 255) / 256, 256, 0, stream>>>(x_proj_w, xw_pad);
        cvt_dtw_pad_kernel<<<(3 * 1536 * 64 / 4 + 255) / 256, 256, 0, stream>>>(dt_proj_w, dtw_pad);
    }

    for (int i = 0; i < N_LAYER; i++) {
        add_rmsnorm_kernel<<<NROWS, 256, 0, stream>>>(
            i == 0 ? hs : hidden, i == 0 ? nullptr : residual,
            norm_w + i * D_MODEL, residual, nullptr, normbf);
        // in_proj: 2048x3072, K=768 — bf16 out
        gemm_mfma_kernel<64, 128, 0, 1, 1><<<dim3(2 * D_INNER / 128, NROWS / 64), 256, 0, stream>>>(
            normbf, win_bf + (size_t)i * 2 * D_INNER * D_MODEL, nullptr,
            xzbf, 2 * D_INNER, 2 * D_INNER, NROWS, D_MODEL);
        conv_silu_kernel<<<NROWS * D_INNER / 256, 256, 0, stream>>>(
            xzbf, conv_w + i * D_INNER * D_CONV, conv_b + i * D_INNER, xconvbf);
        // x_proj: 2048x80(pad128), K=1536, split-K x8
        gemm_mfma_kernel<64, 128, 0, KSPLIT_X, 0><<<dim3(1, NROWS / 64, KSPLIT_X), 256, 0, stream>>>(
            xconvbf, xw_pad + (size_t)i * 128 * 1536, nullptr,
            xpart, XDBL_W, XDBL_W, NROWS, D_INNER);
        xreduce_kernel<<<(NROWS * XDBL_W / 4 + 255) / 256, 256, 0, stream>>>(
            xpart, xdbl, xdtbf);
        // dt_proj: 2048x1536, K=64(pad) — softplus epilogue
        gemm_mfma_kernel<64, 128, 1, 1, 0><<<dim3(D_INNER / 128, NROWS / 64), 256, 0, stream>>>(
            xdtbf, dtw_pad + (size_t)i * 1536 * 64, dt_proj_b + i * D_INNER,
            delta, D_INNER, D_INNER, NROWS, 64);
        // scan: single cooperative dispatch (phase1 -> grid.sync -> phase2)
        {
            const ushort* u_    = xconvbf;
            const float*  dlt_  = delta;
            const float*  alog_ = A_log + (size_t)i * D_INNER * D_STATE;
            const float*  xd_   = xdbl;
            const float*  dsk_  = D_skip + i * D_INNER;
            const ushort* xz_   = xzbf;
            float*        sm_   = summ;
            ushort*       yb_   = ybf;
            void* args[] = {(void*)&u_, (void*)&dlt_, (void*)&alog_, (void*)&xd_,
                            (void*)&dsk_, (void*)&xz_, (void*)&sm_, (void*)&yb_};
            hipLaunchCooperativeKernel((const void*)scan_coop_kernel,
                                       dim3(BATCH * NDG * NSPLIT), dim3(512),
                                       args, 0, stream);
        }
        // out_proj: 2048x768, K=1536
        gemm_mfma_kernel<64, 64, 0, 1, 0><<<dim3(D_MODEL / 64, NROWS / 64), 256, 0, stream>>>(
            ybf, wout_bf + (size_t)i * D_MODEL * D_INNER, nullptr,
            hidden, D_MODEL, D_MODEL, NROWS, D_INNER);
    }
    add_rmsnorm_kernel<<<NROWS, 256, 0, stream>>>(
        hidden, residual, norm_f_w, nullptr, (float*)d_out, nullptr);
}

// Round 9
// 501.937 us; speedup vs baseline: 1.6180x; 1.6180x over previous
//
#include <hip/hip_runtime.h>
#include <math.h>

#define D_MODEL 768
#define D_INNER 1536
#define D_STATE 16
#define D_CONV 4
#define DT_RANK 48
#define N_LAYER 3
#define BATCH 2
#define SEQLEN 1024
#define NROWS (BATCH * SEQLEN)   // 2048
#define XDBL_W (DT_RANK + 2 * D_STATE)  // 80
#define EPS 1e-5f

#define SCLEN 16
#define SDN 16                   // d-channels per scan block

typedef short bf16x8 __attribute__((ext_vector_type(8)));
typedef float f32x4 __attribute__((ext_vector_type(4)));

__device__ __forceinline__ ushort f2bf(float x) {
    union { float f; uint u; } v; v.f = x;
    uint r = v.u + 0x7fff + ((v.u >> 16) & 1);   // RNE
    return (ushort)(r >> 16);
}
__device__ __forceinline__ float bf2f(ushort x) {
    union { uint u; float f; } v; v.u = ((uint)x) << 16;
    return v.f;
}

__device__ __forceinline__ void gload_lds16(const void* g, void* l) {
    __builtin_amdgcn_global_load_lds(
        (const __attribute__((address_space(1))) unsigned int*)g,
        (__attribute__((address_space(3))) unsigned int*)l, 16, 0, 0);
}

// ---------------- all weight conversions in ONE dispatch ----------------
// seg0: in_proj [3][3072][768] f2bf
// seg1: out_proj [3][768][1536] f2bf
// seg2: x_proj pad [3][80][1536] -> [3][128][1536] (rows>=80 zero)
// seg3: dt_proj pad [3][1536][48] -> [3][1536][64] (cols>=48 zero)
#define CVT_N0 (3 * 3072 * 768 / 4)
#define CVT_N1 (3 * 768 * 1536 / 4)
#define CVT_N2 (3 * 128 * 1536 / 4)
#define CVT_N3 (3 * 1536 * 64 / 4)
#define CVT_C1 (CVT_N0)
#define CVT_C2 (CVT_C1 + CVT_N1)
#define CVT_C3 (CVT_C2 + CVT_N2)
#define CVT_TOT (CVT_C3 + CVT_N3)

__global__ __launch_bounds__(256) void cvt_all_kernel(
    const float* __restrict__ w_in, const float* __restrict__ w_out,
    const float* __restrict__ w_x, const float* __restrict__ w_dt,
    ushort* __restrict__ d_in, ushort* __restrict__ d_out,
    ushort* __restrict__ d_x, ushort* __restrict__ d_dt)
{
    int i = blockIdx.x * 256 + threadIdx.x;
    if (i < CVT_C1) {
        float4 v = ((const float4*)w_in)[i];
        ushort4 o; o.x = f2bf(v.x); o.y = f2bf(v.y); o.z = f2bf(v.z); o.w = f2bf(v.w);
        ((ushort4*)d_in)[i] = o;
    } else if (i < CVT_C2) {
        int j = i - CVT_C1;
        float4 v = ((const float4*)w_out)[j];
        ushort4 o; o.x = f2bf(v.x); o.y = f2bf(v.y); o.z = f2bf(v.z); o.w = f2bf(v.w);
        ((ushort4*)d_out)[j] = o;
    } else if (i < CVT_C3) {
        int j = i - CVT_C2;
        const int per = 128 * 1536 / 4;
        int li = j / per, rem = j - li * per;
        int r = (rem * 4) / 1536, c = (rem * 4) % 1536;
        ushort4 o = make_ushort4(0, 0, 0, 0);
        if (r < XDBL_W) {
            const float* s = w_x + ((size_t)li * XDBL_W + r) * 1536 + c;
            o.x = f2bf(s[0]); o.y = f2bf(s[1]); o.z = f2bf(s[2]); o.w = f2bf(s[3]);
        }
        ((ushort4*)d_x)[j] = o;
    } else if (i < CVT_TOT) {
        int j = i - CVT_C3;
        const int per = 1536 * 64 / 4;
        int li = j / per, rem = j - li * per;
        int r = (rem * 4) / 64, c = (rem * 4) % 64;
        ushort4 o = make_ushort4(0, 0, 0, 0);
        if (c < DT_RANK) {
            const float* s = w_dt + ((size_t)li * 1536 + r) * DT_RANK + c;
            o.x = f2bf(s[0]); o.y = f2bf(s[1]); o.z = f2bf(s[2]); o.w = f2bf(s[3]);
        }
        ((ushort4*)d_dt)[j] = o;
    }
}

// ---------------- add + rmsnorm ----------------
__global__ __launch_bounds__(256) void add_rmsnorm_kernel(
    const float* __restrict__ x, const float* __restrict__ res_in,
    const float* __restrict__ w, float* __restrict__ res_out,
    float* __restrict__ normed_f32, ushort* __restrict__ normed_bf)
{
    int row = blockIdx.x;
    int tid = threadIdx.x;
    const float* xr = x + row * D_MODEL;
    float v[3];
    float ss = 0.f;
#pragma unroll
    for (int i = 0; i < 3; i++) {
        int c = tid + i * 256;
        float t = xr[c];
        if (res_in) t += res_in[row * D_MODEL + c];
        v[i] = t;
        ss += t * t;
    }
    for (int off = 32; off; off >>= 1) ss += __shfl_xor(ss, off, 64);
    __shared__ float red[4];
    if ((tid & 63) == 0) red[tid >> 6] = ss;
    __syncthreads();
    float tot = red[0] + red[1] + red[2] + red[3];
    float scale = rsqrtf(tot * (1.f / D_MODEL) + EPS);
#pragma unroll
    for (int i = 0; i < 3; i++) {
        int c = tid + i * 256;
        if (res_out) res_out[row * D_MODEL + c] = v[i];
        float o = v[i] * scale * w[c];
        if (normed_f32) normed_f32[row * D_MODEL + c] = o;
        if (normed_bf)  normed_bf[row * D_MODEL + c] = f2bf(o);
    }
}

// ---------------- bf16 MFMA GEMM: C[M,N] = A[M,K] @ W[N,K]^T ----------------
// EPI: 0 none (f32 or bf16 out per OUTBF), 1 softplus(acc+bias[n]) f32 out,
// 2 dual-out: f32 to Cv (ldc, cc<Nout) AND bf16 to C2 (ld 64, cc<48; zeros
// for 48<=cc<64).
template <int BM, int BN, int EPI, int OUTBF>
__global__ __launch_bounds__(256) void gemm_mfma_kernel(
    const ushort* __restrict__ A, const ushort* __restrict__ W,
    const float* __restrict__ bias, void* __restrict__ Cv,
    ushort* __restrict__ C2, int ldc, int Nout, int M, int K)
{
    constexpr int TM = BM / 32;
    constexpr int TN = BN / 32;
    __shared__ __attribute__((aligned(16))) ushort As[BM * 64];
    __shared__ __attribute__((aligned(16))) ushort Ws[BN * 64];
    const int t = threadIdx.x;
    const int lane = t & 63, w = t >> 6;
    const int ln15 = lane & 15, q = lane >> 4;
    const int row0 = blockIdx.y * BM, col0 = blockIdx.x * BN;
    const int wm0 = (w & 1) * (BM / 2), wn0 = (w >> 1) * (BN / 2);

    float* Cf = (float*)Cv;
    ushort* Cb = (ushort*)Cv;

    f32x4 acc[TM][TN];
#pragma unroll
    for (int i = 0; i < TM; i++)
#pragma unroll
        for (int j = 0; j < TN; j++) acc[i][j] = (f32x4){0.f, 0.f, 0.f, 0.f};

    for (int k0 = 0; k0 < K; k0 += 64) {
        __syncthreads();
#pragma unroll
        for (int i = 0; i < BM / 32; i++) {
            int p = (i * 4 + w) * 64 + lane;
            int r = p >> 3, s = p & 7;
            int g = s ^ (r & 7);
            gload_lds16(A + (size_t)(row0 + r) * K + k0 + g * 8, &As[p * 8]);
        }
#pragma unroll
        for (int i = 0; i < BN / 32; i++) {
            int p = (i * 4 + w) * 64 + lane;
            int r = p >> 3, s = p & 7;
            int g = s ^ (r & 7);
            gload_lds16(W + (size_t)(col0 + r) * K + k0 + g * 8, &Ws[p * 8]);
        }
        __syncthreads();
#pragma unroll
        for (int ks = 0; ks < 2; ks++) {
            bf16x8 af[TM], wf[TN];
#pragma unroll
            for (int im = 0; im < TM; im++) {
                int m = wm0 + im * 16 + ln15;
                int slot = (ks * 4 + q) ^ (m & 7);
                af[im] = *(const bf16x8*)&As[m * 64 + slot * 8];
            }
#pragma unroll
            for (int jn = 0; jn < TN; jn++) {
                int n = wn0 + jn * 16 + ln15;
                int slot = (ks * 4 + q) ^ (n & 7);
                wf[jn] = *(const bf16x8*)&Ws[n * 64 + slot * 8];
            }
#pragma unroll
            for (int im = 0; im < TM; im++)
#pragma unroll
                for (int jn = 0; jn < TN; jn++)
                    acc[im][jn] = __builtin_amdgcn_mfma_f32_16x16x32_bf16(
                        af[im], wf[jn], acc[im][jn], 0, 0, 0);
        }
    }
#pragma unroll
    for (int im = 0; im < TM; im++) {
#pragma unroll
        for (int jn = 0; jn < TN; jn++) {
            int rr = row0 + wm0 + im * 16 + q * 4;
            int cc = col0 + wn0 + jn * 16 + ln15;
#pragma unroll
            for (int r = 0; r < 4; r++) {
                float v = acc[im][jn][r];
                if (EPI == 2) {
                    if (cc < Nout) Cf[(size_t)(rr + r) * ldc + cc] = v;
                    if (cc < DT_RANK)  C2[(size_t)(rr + r) * 64 + cc] = f2bf(v);
                    else if (cc < 64)  C2[(size_t)(rr + r) * 64 + cc] = 0;
                } else if (cc < Nout) {
                    if (EPI == 1) {
                        v += bias[cc];
                        v = (v > 20.f) ? v : log1pf(__expf(v));
                    }
                    if (OUTBF) Cb[(size_t)(rr + r) * ldc + cc] = f2bf(v);
                    else       Cf[(size_t)(rr + r) * ldc + cc] = v;
                }
            }
        }
    }
}

// ---------------- depthwise causal conv1d (k=4) + SiLU (bf16 in/out) -------
__global__ __launch_bounds__(256) void conv_silu_kernel(
    const ushort* __restrict__ xzbf, const float* __restrict__ cw,
    const float* __restrict__ cb, ushort* __restrict__ out_bf)
{
    int idx = blockIdx.x * 256 + threadIdx.x;
    int d = idx % D_INNER;
    int bl = idx / D_INNER;
    int l = bl % SEQLEN;
    float s = cb[d];
    const ushort* xp = xzbf + (size_t)bl * (2 * D_INNER) + d;
#pragma unroll
    for (int k = 0; k < D_CONV; k++) {
        int ls = l - (D_CONV - 1) + k;
        if (ls >= 0) s += cw[d * D_CONV + k] * bf2f(xp[(k - (D_CONV - 1)) * (2 * D_INNER)]);
    }
    float sil = s / (1.f + __expf(-s));
    out_bf[(size_t)bl * D_INNER + d] = f2bf(sil);
}

// ---------------- coalesced chunked selective scan (proven round-4/6 form) --
// 1024 threads: dsub = lane&15 (16 consecutive d), csub = lane>>4 (4 chunks/
// wave), 16 waves -> 64 chunks. Intra-wave shfl scan + LDS cross-wave serial
// compose. u and z read as bf16; y written bf16.
__global__ __launch_bounds__(1024) void scan2_kernel(
    const ushort* __restrict__ ubf, const float* __restrict__ delta,
    const float* __restrict__ A_log, const float* __restrict__ xdbl,
    const float* __restrict__ Dskip, const ushort* __restrict__ xzbf,
    ushort* __restrict__ ybf)
{
    __shared__ float PL[16][SDN * 17];
    __shared__ float HL[16][SDN * 17];
    const int t = threadIdx.x;
    const int lane = t & 63;
    const int w = t >> 6;             // wave 0..15
    const int dsub = lane & 15;
    const int csub = lane >> 4;       // 0..3
    const int c = w * 4 + csub;       // chunk 0..63
    const int b = blockIdx.x / (D_INNER / SDN);
    const int d = (blockIdx.x % (D_INNER / SDN)) * SDN + dsub;

    float a2[D_STATE];
#pragma unroll
    for (int n = 0; n < D_STATE; n++)
        a2[n] = -__expf(A_log[d * D_STATE + n]) * 1.44269504f;

    const size_t base = (size_t)b * SEQLEN * D_INNER + d;
    const float* dtp = delta + base;
    const ushort* up = ubf + base;
    const float* xrow = xdbl + (size_t)b * SEQLEN * XDBL_W;
    const int l0 = c * SCLEN;

    float h[D_STATE], P[D_STATE];
#pragma unroll
    for (int n = 0; n < D_STATE; n++) { h[n] = 0.f; P[n] = 1.f; }

    // ---- phase 1: chunk transfer ----
    for (int i = 0; i < SCLEN; i++) {
        const int l = l0 + i;
        float dt = dtp[(size_t)l * D_INNER];
        float uu = bf2f(up[(size_t)l * D_INNER]);
        const float4* Bv = (const float4*)(xrow + (size_t)l * XDBL_W + DT_RANK);
        float4 q0 = Bv[0], q1 = Bv[1], q2 = Bv[2], q3 = Bv[3];
        float Bf[D_STATE] = {q0.x,q0.y,q0.z,q0.w, q1.x,q1.y,q1.z,q1.w,
                             q2.x,q2.y,q2.z,q2.w, q3.x,q3.y,q3.z,q3.w};
        float dtu = dt * uu;
#pragma unroll
        for (int n = 0; n < D_STATE; n++) {
            float e = __builtin_amdgcn_exp2f(dt * a2[n]);
            P[n] *= e;
            h[n] = e * h[n] + dtu * Bf[n];
        }
    }

    // ---- intra-wave inclusive scan over csub ----
#pragma unroll
    for (int n = 0; n < D_STATE; n++) {
        float Pp = __shfl(P[n], lane - 16, 64);
        float Hp = __shfl(h[n], lane - 16, 64);
        bool act = csub >= 1;
        h[n] = act ? P[n] * Hp + h[n] : h[n];
        P[n] = act ? P[n] * Pp : P[n];
    }
#pragma unroll
    for (int n = 0; n < D_STATE; n++) {
        float Pp = __shfl(P[n], lane - 32, 64);
        float Hp = __shfl(h[n], lane - 32, 64);
        bool act = csub >= 2;
        h[n] = act ? P[n] * Hp + h[n] : h[n];
        P[n] = act ? P[n] * Pp : P[n];
    }

    if (csub == 3) {
#pragma unroll
        for (int n = 0; n < D_STATE; n++) {
            PL[w][dsub * 17 + n] = P[n];
            HL[w][dsub * 17 + n] = h[n];
        }
    }
    __syncthreads();

    if (t < SDN * D_STATE) {
        const int d2 = t >> 4, n2 = t & 15;
        float hin = 0.f;
        for (int ww = 0; ww < 16; ww++) {
            float Pw = PL[ww][d2 * 17 + n2];
            float Hw = HL[ww][d2 * 17 + n2];
            HL[ww][d2 * 17 + n2] = hin;
            hin = Pw * hin + Hw;
        }
    }
    __syncthreads();

#pragma unroll
    for (int n = 0; n < D_STATE; n++) {
        float Win = HL[w][dsub * 17 + n];
        float Pe = __shfl(P[n], lane - 16, 64);
        float He = __shfl(h[n], lane - 16, 64);
        h[n] = (csub == 0) ? Win : Pe * Win + He;
    }

    // ---- phase 2: rescan with true h0, gate, emit y ----
    const float Dsk = Dskip[d];
    const ushort* zp = xzbf + (size_t)b * SEQLEN * (2 * D_INNER) + D_INNER + d;
    ushort* yp = ybf + base;
    for (int i = 0; i < SCLEN; i++) {
        const int l = l0 + i;
        float dt = dtp[(size_t)l * D_INNER];
        float uu = bf2f(up[(size_t)l * D_INNER]);
        float zz = bf2f(zp[(size_t)l * (2 * D_INNER)]);
        const float4* Bv = (const float4*)(xrow + (size_t)l * XDBL_W + DT_RANK);
        float4 q0 = Bv[0], q1 = Bv[1], q2 = Bv[2], q3 = Bv[3];
        float4 r0 = Bv[4], r1 = Bv[5], r2 = Bv[6], r3 = Bv[7];
        float Bf[D_STATE] = {q0.x,q0.y,q0.z,q0.w, q1.x,q1.y,q1.z,q1.w,
                             q2.x,q2.y,q2.z,q2.w, q3.x,q3.y,q3.z,q3.w};
        float Cf[D_STATE] = {r0.x,r0.y,r0.z,r0.w, r1.x,r1.y,r1.z,r1.w,
                             r2.x,r2.y,r2.z,r2.w, r3.x,r3.y,r3.z,r3.w};
        float dtu = dt * uu;
        float acc = 0.f;
#pragma unroll
        for (int n = 0; n < D_STATE; n++) {
            float e = __builtin_amdgcn_exp2f(dt * a2[n]);
            h[n] = e * h[n] + dtu * Bf[n];
            acc += h[n] * Cf[n];
        }
        float yy = acc + uu * Dsk;
        float ee = __builtin_amdgcn_exp2f(-zz * 1.44269504f);
        float sil = zz * __builtin_amdgcn_rcpf(1.f + ee);
        yp[(size_t)l * D_INNER] = f2bf(yy * sil);
    }
}

extern "C" void kernel_launch(void* const* d_in, const int* in_sizes, int n_in,
                              void* d_out, int out_size, void* d_ws, size_t ws_size,
                              hipStream_t stream)
{
    const float* hs        = (const float*)d_in[0];
    const float* norm_w    = (const float*)d_in[1];
    const float* in_proj_w = (const float*)d_in[2];
    const float* conv_w    = (const float*)d_in[3];
    const float* conv_b    = (const float*)d_in[4];
    const float* x_proj_w  = (const float*)d_in[5];
    const float* dt_proj_w = (const float*)d_in[6];
    const float* dt_proj_b = (const float*)d_in[7];
    const float* A_log     = (const float*)d_in[8];
    const float* D_skip    = (const float*)d_in[9];
    const float* out_proj_w= (const float*)d_in[10];
    const float* norm_f_w  = (const float*)d_in[11];

    float* ws = (float*)d_ws;
    float* residual = ws;                                   // 2048*768
    float* hidden   = residual + NROWS * D_MODEL;           // 2048*768
    float* xdbl     = hidden + NROWS * D_MODEL;             // 2048*80
    float* delta    = xdbl + NROWS * XDBL_W;                // 2048*1536
    ushort* xzbf    = (ushort*)(delta + NROWS * D_INNER);   // 2048*3072
    ushort* normbf  = xzbf + (size_t)NROWS * 2 * D_INNER;   // 2048*768
    ushort* ybf     = normbf + NROWS * D_MODEL;             // 2048*1536
    ushort* xconvbf = ybf + NROWS * D_INNER;                // 2048*1536
    ushort* xdtbf   = xconvbf + NROWS * D_INNER;            // 2048*64
    ushort* win_bf  = xdtbf + NROWS * 64;                   // 3*3072*768
    ushort* wout_bf = win_bf + (size_t)N_LAYER * 2 * D_INNER * D_MODEL;
    ushort* xw_pad  = wout_bf + (size_t)N_LAYER * D_MODEL * D_INNER; // 3*128*1536
    ushort* dtw_pad = xw_pad + (size_t)N_LAYER * 128 * 1536;          // 3*1536*64

    // all weight conversions in one dispatch
    cvt_all_kernel<<<(CVT_TOT + 255) / 256, 256, 0, stream>>>(
        in_proj_w, out_proj_w, x_proj_w, dt_proj_w,
        win_bf, wout_bf, xw_pad, dtw_pad);

    for (int i = 0; i < N_LAYER; i++) {
        add_rmsnorm_kernel<<<NROWS, 256, 0, stream>>>(
            i == 0 ? hs : hidden, i == 0 ? nullptr : residual,
            norm_w + i * D_MODEL, residual, nullptr, normbf);
        // in_proj: 2048x3072, K=768 — bf16 out, 768 blocks
        gemm_mfma_kernel<64, 128, 0, 1><<<dim3(2 * D_INNER / 128, NROWS / 64), 256, 0, stream>>>(
            normbf, win_bf + (size_t)i * 2 * D_INNER * D_MODEL, nullptr,
            xzbf, nullptr, 2 * D_INNER, 2 * D_INNER, NROWS, D_MODEL);
        conv_silu_kernel<<<NROWS * D_INNER / 256, 256, 0, stream>>>(
            xzbf, conv_w + i * D_INNER * D_CONV, conv_b + i * D_INNER, xconvbf);
        // x_proj: 2048x80(pad128), K=1536 — dual out (f32 xdbl + bf16 xdt)
        gemm_mfma_kernel<32, 128, 2, 0><<<dim3(1, NROWS / 32), 256, 0, stream>>>(
            xconvbf, xw_pad + (size_t)i * 128 * 1536, nullptr,
            xdbl, xdtbf, XDBL_W, XDBL_W, NROWS, D_INNER);
        // dt_proj: 2048x1536, K=64(pad) — softplus epilogue, 384 blocks
        gemm_mfma_kernel<64, 128, 1, 0><<<dim3(D_INNER / 128, NROWS / 64), 256, 0, stream>>>(
            xdtbf, dtw_pad + (size_t)i * 1536 * 64, dt_proj_b + i * D_INNER,
            delta, nullptr, D_INNER, D_INNER, NROWS, 64);
        // scan: proven single-dispatch form (bf16 u/z)
        scan2_kernel<<<BATCH * (D_INNER / SDN), 1024, 0, stream>>>(
            xconvbf, delta, A_log + (size_t)i * D_INNER * D_STATE, xdbl,
            D_skip + i * D_INNER, xzbf, ybf);
        // out_proj: 2048x768, K=1536
        gemm_mfma_kernel<64, 64, 0, 0><<<dim3(D_MODEL / 64, NROWS / 64), 256, 0, stream>>>(
            ybf, wout_bf + (size_t)i * D_MODEL * D_INNER, nullptr,
            hidden, nullptr, D_MODEL, D_MODEL, NROWS, D_INNER);
    }
    add_rmsnorm_kernel<<<NROWS, 256, 0, stream>>>(
        hidden, residual, norm_f_w, nullptr, (float*)d_out, nullptr);
}